// Round 3
// baseline (11.299 us; speedup 1.0000x reference)
//
#include <hip/hip_runtime.h>

// Problem: DIM=64, N=64, M=2*DIM*N+1=8193
//   mat:          (DIM, N)  f32   mat[d*64 + n]
//   weights_sort: (M, DIM)  f32   ws[m*64 + d]
//   weights_dot:  (M, N)    f32   wd[m*64 + n]
// reference:
//   s[n,m]   = sum_d mat[d,n] * ws[m,d]
//   col_sorted[:,m] = sort(s[:,m])          (ascending over n)
//   out[m]   = sum_n wd[m,n] * col_sorted[n,m]
//
// R2 change: 4 m's per wave. The 21-step bitonic sort is a serial
// ds_swizzle latency chain; interleaving 4 independent sorts gives 4-way
// ILP on the DS pipe. mat loads amortize 4x (value reused in 4 FMAs with
// different scalar ws operands). Wave count 8193 -> 2049.

#define DIMC 64
#define NC   64
#define MC   8193
#define MPW  4   // m's per wave
#define WPB  4   // waves per block (256 threads)

__global__ __launch_bounds__(256) void embed_kernel(
    const float* __restrict__ mat,
    const float* __restrict__ ws,
    const float* __restrict__ wd,
    float* __restrict__ out)
{
    const int lane = threadIdx.x & 63;
    // Wave-uniform base m, provably so -> scalar loads for ws rows.
    const int wave = __builtin_amdgcn_readfirstlane(blockIdx.x * WPB + (threadIdx.x >> 6));
    const int m0 = wave * MPW;
    if (m0 >= MC) return;
    const int mlim = MC - m0;  // >=1; ==1 only for the last wave (m0=8192)

    // Row pointers, clamped for the tail wave (avoids OOB reads; results
    // for clamped rows are discarded at the store).
    const float* __restrict__ wsr[MPW];
#pragma unroll
    for (int i = 0; i < MPW; ++i) {
        int r = m0 + i; if (r > MC - 1) r = MC - 1;
        wsr[i] = ws + r * DIMC;
    }

    // s[i][lane] = sum_d mat[d][lane] * ws[m0+i][d]
    // One coalesced mat load per d, reused by 4 FMAs (scalar second operand).
    float s[MPW] = {0.f, 0.f, 0.f, 0.f};
#pragma unroll
    for (int d = 0; d < DIMC; ++d) {
        const float mv = mat[d * NC + lane];
        s[0] = fmaf(mv, wsr[0][d], s[0]);
        s[1] = fmaf(mv, wsr[1][d], s[1]);
        s[2] = fmaf(mv, wsr[2][d], s[2]);
        s[3] = fmaf(mv, wsr[3][d], s[3]);
    }

    // 4 interleaved bitonic sorts (ascending) across the 64 lanes.
#pragma unroll
    for (int k = 2; k <= 64; k <<= 1) {
#pragma unroll
        for (int j = k >> 1; j > 0; j >>= 1) {
            const bool keep_min = (((lane & j) == 0) == ((lane & k) == 0));
#pragma unroll
            for (int i = 0; i < MPW; ++i) {
                const float p = __shfl_xor(s[i], j);
                s[i] = keep_min ? fminf(s[i], p) : fmaxf(s[i], p);
            }
        }
    }

    // prod[i] = wd[m0+i][lane] * sorted_i[lane]; 4 interleaved reductions.
    float prod[MPW];
#pragma unroll
    for (int i = 0; i < MPW; ++i) {
        int r = m0 + i; if (r > MC - 1) r = MC - 1;
        prod[i] = wd[r * NC + lane] * s[i];
    }
#pragma unroll
    for (int off = 32; off > 0; off >>= 1) {
#pragma unroll
        for (int i = 0; i < MPW; ++i) prod[i] += __shfl_xor(prod[i], off);
    }

    if (lane == 0) {
        if (mlim >= MPW) {
            *reinterpret_cast<float4*>(out + m0) =
                make_float4(prod[0], prod[1], prod[2], prod[3]);
        } else {
#pragma unroll
            for (int i = 0; i < MPW; ++i)
                if (i < mlim) out[m0 + i] = prod[i];
        }
    }
}

extern "C" void kernel_launch(void* const* d_in, const int* in_sizes, int n_in,
                              void* d_out, int out_size, void* d_ws, size_t ws_size,
                              hipStream_t stream) {
    const float* mat = (const float*)d_in[0];
    const float* ws  = (const float*)d_in[1];
    const float* wd  = (const float*)d_in[2];
    float* out = (float*)d_out;

    const int m_per_block = MPW * WPB;  // 16
    const int grid = (MC + m_per_block - 1) / m_per_block;  // 513
    embed_kernel<<<grid, 256, 0, stream>>>(mat, ws, wd, out);
}

// Round 4
// 11.087 us; speedup vs baseline: 1.0191x; 1.0191x over previous
//
#include <hip/hip_runtime.h>

// Problem: DIM=64, N=64, M=2*DIM*N+1=8193
//   mat:          (DIM, N)  f32   mat[d*64 + n]
//   weights_sort: (M, DIM)  f32   ws[m*64 + d]
//   weights_dot:  (M, N)    f32   wd[m*64 + n]
// reference:
//   s[n,m]   = sum_d mat[d,n] * ws[m,d]
//   col_sorted[:,m] = sort(s[:,m])          (ascending over n)
//   out[m]   = sum_n wd[m,n] * col_sorted[n,m]
//
// Final (R4): revert to the best-measured R1 structure. One 64-lane wave
// per m; ws row fetched via wave-uniform scalar loads (readfirstlane'd m);
// 4-way accumulator split for FMA ILP; 21-step bitonic sort across the
// wave via __shfl_xor; 6-step wave reduce for the final dot.
//
// Measured history: R0 shfl-broadcast matvec = 15.0 us; R1 (this) = 11.03 us;
// R2/R3 4-m batching (4x fewer waves) = 11.03/11.30 us -> dur is pinned at
// the ~10 us fixed launch/replay overhead; kernel execution is ~1-2 us
// (aggregated VALUBusy across replays / replay count). Memory floor 0.7 us,
// compute floor ~1 us -> overhead-bound, not a HW roofline issue.

#define DIMC 64
#define NC   64
#define MC   8193
#define WPB  4   // waves per block (256 threads)

__global__ __launch_bounds__(256) void embed_kernel(
    const float* __restrict__ mat,
    const float* __restrict__ ws,
    const float* __restrict__ wd,
    float* __restrict__ out)
{
    const int lane = threadIdx.x & 63;
    // Wave-uniform m, provably so for the compiler -> scalar loads for ws row.
    const int m = __builtin_amdgcn_readfirstlane(blockIdx.x * WPB + (threadIdx.x >> 6));
    if (m >= MC) return;

    const float* __restrict__ wsrow = ws + m * DIMC;  // uniform address

    // s[lane] = sum_d mat[d][lane] * ws[m][d]
    // mat loads: one coalesced wave load per d, L1-resident (16 KB total).
    // wsrow[d]: scalar (SGPR) loads via s_load_dwordx16, zero broadcast cost.
    float s0 = 0.0f, s1 = 0.0f, s2 = 0.0f, s3 = 0.0f;
#pragma unroll
    for (int d = 0; d < DIMC; d += 4) {
        s0 = fmaf(mat[(d + 0) * NC + lane], wsrow[d + 0], s0);
        s1 = fmaf(mat[(d + 1) * NC + lane], wsrow[d + 1], s1);
        s2 = fmaf(mat[(d + 2) * NC + lane], wsrow[d + 2], s2);
        s3 = fmaf(mat[(d + 3) * NC + lane], wsrow[d + 3], s3);
    }
    float s = (s0 + s1) + (s2 + s3);

    // Bitonic sort ascending across the 64 lanes (21 compare-exchanges).
#pragma unroll
    for (int k = 2; k <= 64; k <<= 1) {
#pragma unroll
        for (int j = k >> 1; j > 0; j >>= 1) {
            const float partner = __shfl_xor(s, j);
            const bool up = ((lane & k) == 0);
            const bool keep_min = (((lane & j) == 0) == up);
            s = keep_min ? fminf(s, partner) : fmaxf(s, partner);
        }
    }

    // out[m] = sum_n wd[m][n] * sorted[n]
    float prod = wd[m * NC + lane] * s;
#pragma unroll
    for (int off = 32; off > 0; off >>= 1) {
        prod += __shfl_xor(prod, off);
    }
    if (lane == 0) out[m] = prod;
}

extern "C" void kernel_launch(void* const* d_in, const int* in_sizes, int n_in,
                              void* d_out, int out_size, void* d_ws, size_t ws_size,
                              hipStream_t stream) {
    const float* mat = (const float*)d_in[0];
    const float* ws  = (const float*)d_in[1];
    const float* wd  = (const float*)d_in[2];
    float* out = (float*)d_out;

    const int grid = (MC + WPB - 1) / WPB;  // 2049 blocks of 256 threads
    embed_kernel<<<grid, 256, 0, stream>>>(mat, ws, wd, out);
}